// Round 3
// baseline (534.498 us; speedup 1.0000x reference)
//
#include <hip/hip_runtime.h>

typedef unsigned short UST;
typedef __attribute__((ext_vector_type(8))) short bf16x8;
typedef __attribute__((ext_vector_type(8))) unsigned short us8;
typedef __attribute__((ext_vector_type(4))) float f32x4;

__device__ __forceinline__ UST f2bf(float f) {
  union { float f; unsigned int u; } x; x.f = f;
  unsigned int r = x.u + 0x7fffu + ((x.u >> 16) & 1u);
  return (UST)(r >> 16);
}
__device__ __forceinline__ float bf2f(UST h) {
  union { unsigned int u; float f; } x; x.u = ((unsigned int)h) << 16;
  return x.f;
}

// sync_lds drains LDS ops only (NOT vmcnt) then barriers.
__device__ __forceinline__ void sync_lds() {
  asm volatile("s_waitcnt lgkmcnt(0)\n\ts_barrier" ::: "memory");
}
__device__ __forceinline__ void barrier_nowait() {
  asm volatile("s_barrier" ::: "memory");
}

typedef const __attribute__((address_space(1))) void g_void;
typedef __attribute__((address_space(3))) void lds_void;
// async global->LDS, 16B per lane; LDS dest = wave-uniform base + lane*16
__device__ __forceinline__ void gload16(const UST* g, UST* l) {
  __builtin_amdgcn_global_load_lds((g_void*)g, (lds_void*)l, 16, 0, 0);
}

// ---- prep: GroupNorm (0..511, SINGLE PASS: data lives in 64 VGPRs) ---------
// + weight conversion (512..767) + zero l (768..783)
// Xnt layout per batch: element (n,c) at (c>>3)*8192 + n*8 + (c&7)  [bf16]
__global__ __launch_bounds__(256) void prep(
    const float* __restrict__ inp, const float* __restrict__ gamma,
    const float* __restrict__ beta, UST* __restrict__ Xnt,
    const float4* __restrict__ wq, const float4* __restrict__ wk,
    const float4* __restrict__ wv, const float4* __restrict__ wo,
    ushort4* __restrict__ oqkv, ushort4* __restrict__ owo,
    const float4* __restrict__ bq4, const float4* __restrict__ bk4,
    const float4* __restrict__ bv4, float4* __restrict__ bqkv4,
    float4* __restrict__ l4) {
  const int tid = threadIdx.x;
  if (blockIdx.x >= 768) {  // zero the softmax-denominator array (16384 f32)
    int i = (blockIdx.x - 768) * 256 + tid;
    l4[i] = make_float4(0.f, 0.f, 0.f, 0.f);
    return;
  }
  if (blockIdx.x >= 512) {
    const int wb = blockIdx.x - 512;       // 0..255
    int i = wb * 256 + tid;                // 65536 float4 per matrix
    float4 v;
    v = wq[i]; oqkv[i]          = make_ushort4(f2bf(v.x), f2bf(v.y), f2bf(v.z), f2bf(v.w));
    v = wk[i]; oqkv[i + 65536]  = make_ushort4(f2bf(v.x), f2bf(v.y), f2bf(v.z), f2bf(v.w));
    v = wv[i]; oqkv[i + 131072] = make_ushort4(f2bf(v.x), f2bf(v.y), f2bf(v.z), f2bf(v.w));
    v = wo[i]; owo[i]           = make_ushort4(f2bf(v.x), f2bf(v.y), f2bf(v.z), f2bf(v.w));
    if (wb < 2) {
      int t = wb * 256 + tid;
      if (t < 384) bqkv4[t] = (t < 128) ? bq4[t] : (t < 256 ? bk4[t - 128] : bv4[t - 256]);
    }
    return;
  }
  // GroupNorm: one block per (batch b, group g). Group = 16 channels x 1024 px
  // = 64KB fp32 = 64 floats/thread: thread holds channel c_local=i, n=4*tid+m.
  const int g = blockIdx.x & 31, b = blockIdx.x >> 5;
  const float4* p4 = (const float4*)(inp + ((size_t)b * 32 + g) * 16384);
  float x[16][4];
  float s = 0.f, ss = 0.f;
#pragma unroll
  for (int i = 0; i < 16; i++) {
    float4 t = p4[tid + i * 256];
    x[i][0] = t.x; x[i][1] = t.y; x[i][2] = t.z; x[i][3] = t.w;
    s += t.x + t.y + t.z + t.w;
    ss += t.x * t.x + t.y * t.y + t.z * t.z + t.w * t.w;
  }
  for (int o = 32; o >= 1; o >>= 1) { s += __shfl_xor(s, o); ss += __shfl_xor(ss, o); }
  __shared__ float red[8];
  __shared__ float mu_s, rstd_s;
  const int w = tid >> 6;
  if ((tid & 63) == 0) { red[w * 2] = s; red[w * 2 + 1] = ss; }
  __syncthreads();
  if (tid == 0) {
    float S1 = red[0] + red[2] + red[4] + red[6];
    float S2 = red[1] + red[3] + red[5] + red[7];
    float mu = S1 * (1.f / 16384.f);
    float var = S2 * (1.f / 16384.f) - mu * mu;
    mu_s = mu; rstd_s = rsqrtf(var + 1e-6f);
  }
  __syncthreads();
  const float mu = mu_s, rstd = rstd_s;
#pragma unroll
  for (int o2 = 0; o2 < 2; o2++) {
    const int ccg = g * 2 + o2;
    float sc[8], sh[8];
#pragma unroll
    for (int j = 0; j < 8; j++) {
      int ch = ccg * 8 + j;
      sc[j] = gamma[ch] * rstd;
      sh[j] = beta[ch] - mu * sc[j];
    }
#pragma unroll
    for (int m = 0; m < 4; m++) {
      us8 v;
#pragma unroll
      for (int j = 0; j < 8; j++) v[j] = f2bf(x[o2 * 8 + j][m] * sc[j] + sh[j]);
      *(us8*)(Xnt + (size_t)b * 524288 + (size_t)ccg * 8192 + (size_t)(4 * tid + m) * 8) = v;
    }
  }
}

// ---- gemm_bt v4: C[i][j] = sum_k A[i][k]*B[j][k] ---------------------------
// 128x128 tile, 4 waves of 64x64, 16 MFMA/iter. Staging: global_load_lds
// direct to LDS, TWO 16KB buffers = 32KB -> 5 blocks/CU (LDS 160KB exactly,
// 20 waves/CU). Depth-2 counted prefetch: steady state 8 loads outstanding,
// s_waitcnt vmcnt(4) per iter (drain only at last iter). Two barriers/iter
// (m97-proven pattern), STAGE(k+2) issued right after the read-completion
// barrier. Max TLP covers ds_read/MFMA latency bubbles (r2 postmortem: 12
// waves/CU was latency-starved at MfmaUtil ~20%).
// Staging scheme per operand (AR/BR template flags):
//   row-minor (AR=1, for Xnt rs==8): LDS = [kc-plane 2KB][row*16B]; global
//     loads 1KB contiguous per instr; reads swizzle-free, 2-way/phase (floor).
//   kc-minor (0, row-major operands): LDS = [row][slot] pitch 32 UST with
//     XOR content swizzle (slot c holds chunk c^s(row), s=((r>>1)^(r>>3))&3)
//     applied on the GLOBAL source address (LDS dest linear, rule #21) and on
//     the ds_read side -> 2-way/phase (floor).
// EPI 6: QKV - bf16 +bias[col]; n0<1024 -> QKt row-major; n0>=1024 -> V
//        transposed into (c,m) layout (V base via `extra`, z-stride 524288)
// EPI 7: P = exp(acc*scale) bf16 + per-row sum atomicAdd into `extra` (l array)
// EPI 8: bf16, acc * (1/l[row]) with l via `bias`  (softmax denominator)
// EPI 4: f32 +bias[row] +extra (residual)
template <int EPI, int NT, int AR, int BR>
__global__ __launch_bounds__(256, 5) void gemm_bt(
    const UST* __restrict__ A, const UST* __restrict__ B, void* __restrict__ C,
    const float* __restrict__ bias, const float* __restrict__ extra, float scale,
    int K, int ldc,
    int rsA, int csA, int ssA, int rsB, int csB, int ssB,
    long zA, long zB, long zC) {
  // 32KB: two (A 8KB + B 8KB) staging buffers; epilogue aliases buf.
  __shared__ __align__(16) UST buf[16384];

  const int tid = threadIdx.x;
  int m0, n0, z;
  if constexpr (NT > 0) {
    int lin = blockIdx.x + NT * (blockIdx.y + gridDim.y * blockIdx.z);
    int T = gridDim.y * gridDim.z;      // total A-tiles (multiple of 8)
    int per = T >> 3;                   // A-tiles per XCD
    int g = lin & 7, idx = lin >> 3;
    int at = g * per + idx / NT;
    int x = idx % NT;
    m0 = (at % gridDim.y) * 128; z = at / gridDim.y; n0 = x * 128;
  } else {
    m0 = blockIdx.y * 128; n0 = blockIdx.x * 128; z = blockIdx.z;
  }
  const UST* Ab = A + (long)z * zA;
  const UST* Bb = B + (long)z * zB;

  const int w = tid >> 6, lane = tid & 63;
  const int quad = lane >> 4, l16 = lane & 15;
  const int wm = w >> 1, wn = w & 1;  // 2x2 waves, each 64x64

  f32x4 acc[4][4];
#pragma unroll
  for (int i = 0; i < 4; i++)
#pragma unroll
    for (int j = 0; j < 4; j++) acc[i][j] = f32x4{0.f, 0.f, 0.f, 0.f};

  // Staging source pointers: 2 rounds each for A and B (512 16B-chunks each).
  const UST* gA[2];
  const UST* gB[2];
#pragma unroll
  for (int t = 0; t < 2; t++) {
    int q = t * 256 + w * 64 + lane;
    int row, kc;
    if constexpr (AR) { kc = q >> 7; row = q & 127; }
    else {
      row = q >> 2; int kk = q & 3;
      kc = kk ^ (((row >> 1) ^ (row >> 3)) & 3);
    }
    gA[t] = Ab + (size_t)(m0 + row) * rsA + (size_t)kc * csA;
  }
#pragma unroll
  for (int t = 0; t < 2; t++) {
    int q = t * 256 + w * 64 + lane;
    int row, kc;
    if constexpr (BR) { kc = q >> 7; row = q & 127; }
    else {
      row = q >> 2; int kk = q & 3;
      kc = kk ^ (((row >> 1) ^ (row >> 3)) & 3);
    }
    gB[t] = Bb + (size_t)(n0 + row) * rsB + (size_t)kc * csB;
  }
  // LDS fragment read offsets (loop-invariant, UST units)
  int aoff[4], boff[4];
#pragma unroll
  for (int i = 0; i < 4; i++) {
    int R = wm * 64 + i * 16 + l16;
    if constexpr (AR) aoff[i] = quad * 1024 + R * 8;
    else {
      int s = ((R >> 1) ^ (R >> 3)) & 3;
      aoff[i] = R * 32 + (quad ^ s) * 8;
    }
  }
#pragma unroll
  for (int j = 0; j < 4; j++) {
    int R = wn * 64 + j * 16 + l16;
    if constexpr (BR) boff[j] = quad * 1024 + R * 8;
    else {
      int s = ((R >> 1) ^ (R >> 3)) & 3;
      boff[j] = R * 32 + (quad ^ s) * 8;
    }
  }

  const int nk = K >> 5;

#define STAGE(bb)                                   \
  {                                                 \
    UST* sA = buf + (bb) * 8192;                    \
    UST* sB = sA + 4096;                            \
    _Pragma("unroll") for (int t = 0; t < 2; t++) { \
      gload16(gA[t], sA + t * 2048 + w * 512);      \
      gA[t] += ssA;                                 \
    }                                               \
    _Pragma("unroll") for (int t = 0; t < 2; t++) { \
      gload16(gB[t], sB + t * 2048 + w * 512);      \
      gB[t] += ssB;                                 \
    }                                               \
  }

  STAGE(0)
  STAGE(1)

  for (int k = 0; k < nk; ++k) {
    // wait for OWN buf[k&1] loads (oldest 4); barrier makes it global.
    if (k + 1 < nk) asm volatile("s_waitcnt vmcnt(4)" ::: "memory");
    else            asm volatile("s_waitcnt vmcnt(0)" ::: "memory");
    barrier_nowait();
    const UST* cA = buf + (k & 1) * 8192;
    const UST* cB = cA + 4096;
    bf16x8 af[4], bfr[4];
#pragma unroll
    for (int i = 0; i < 4; i++) af[i] = *(const bf16x8*)(cA + aoff[i]);
#pragma unroll
    for (int j = 0; j < 4; j++) bfr[j] = *(const bf16x8*)(cB + boff[j]);
    __builtin_amdgcn_s_setprio(1);
#pragma unroll
    for (int i = 0; i < 4; i++)
#pragma unroll
      for (int j = 0; j < 4; j++)
        acc[i][j] = __builtin_amdgcn_mfma_f32_16x16x32_bf16(af[i], bfr[j], acc[i][j], 0, 0, 0);
    __builtin_amdgcn_s_setprio(0);
    if (k + 2 < nk) {
      sync_lds();     // all waves' reads of buf[k&1] done -> safe to overwrite
      STAGE(k & 1)
    }
  }
  sync_lds();  // pre-epilogue barrier (staging -> C-tile reuse)

  // C/D layout (verified m89/m91): col = lane&15, row = quad*4 + reg
  if constexpr (EPI == 4) {
    // fp32 out + bias[row] + residual; four 32-row x 132-float phases
    float* fbuf = (float*)buf;
    float* Cb = (float*)C + (long)z * zC;
    const float* Eb = extra + (long)z * zC;
#pragma unroll
    for (int p = 0; p < 4; ++p) {
      if (p) barrier_nowait();
      if (wm == (p >> 1)) {
#pragma unroll
        for (int ii = 0; ii < 2; ii++) {
          const int i = (p & 1) * 2 + ii;
#pragma unroll
          for (int j = 0; j < 4; j++)
#pragma unroll
            for (int r = 0; r < 4; r++)
              fbuf[(ii * 16 + quad * 4 + r) * 132 + wn * 64 + j * 16 + l16] = acc[i][j][r];
        }
      }
      sync_lds();
#pragma unroll
      for (int it = 0; it < 4; ++it) {
        int q = tid + it * 256;
        int row = q >> 5, colc = q & 31;
        int gr = m0 + p * 32 + row;
        size_t off = (size_t)gr * ldc + n0 + colc * 4;
        float4 v = *(float4*)&fbuf[row * 132 + colc * 4];
        float4 e = *(const float4*)&Eb[off];
        float bb = bias[gr];
        v.x += bb + e.x; v.y += bb + e.y; v.z += bb + e.z; v.w += bb + e.w;
        *(float4*)&Cb[off] = v;
      }
    }
  } else if constexpr (EPI == 7) {
    // P = exp(acc*scale) bf16 + per-row partial sums atomically into l
    UST* Cb = (UST*)C + (long)z * zC;
    float* lrow = (float*)extra + (long)z * 1024;
#pragma unroll
    for (int h = 0; h < 2; ++h) {
      if (h) barrier_nowait();
      if (wm == h) {
#pragma unroll
        for (int i = 0; i < 4; i++)
#pragma unroll
          for (int j = 0; j < 4; j++)
#pragma unroll
            for (int r = 0; r < 4; r++) {
              float v = __expf(acc[i][j][r] * scale);
              buf[(i * 16 + quad * 4 + r) * 136 + wn * 64 + j * 16 + l16] = f2bf(v);
            }
      }
      sync_lds();
#pragma unroll
      for (int it = 0; it < 4; ++it) {
        int q = tid + it * 256;
        int row = q >> 4, colc = q & 15;  // 64 rows x 16 us8
        us8 v = *(us8*)&buf[row * 136 + colc * 8];
        *(us8*)&Cb[(size_t)(m0 + h * 64 + row) * ldc + n0 + colc * 8] = v;
        float s = 0.f;
#pragma unroll
        for (int j = 0; j < 8; j++) s += bf2f(v[j]);
        s += __shfl_xor(s, 8); s += __shfl_xor(s, 4);
        s += __shfl_xor(s, 2); s += __shfl_xor(s, 1);
        if ((lane & 15) == 0) atomicAdd(&lrow[m0 + h * 64 + row], s);
      }
    }
  } else if constexpr (EPI == 8) {
    // At = acc / l[row]  (softmax denominator), bf16 row-major
    UST* Cb = (UST*)C + (long)z * zC;
    const float* lrow = bias + (long)z * 1024;
#pragma unroll
    for (int h = 0; h < 2; ++h) {
      if (h) barrier_nowait();
      if (wm == h) {
#pragma unroll
        for (int i = 0; i < 4; i++) {
          float rs[4];
#pragma unroll
          for (int r = 0; r < 4; r++)
            rs[r] = 1.0f / lrow[m0 + h * 64 + i * 16 + quad * 4 + r];
#pragma unroll
          for (int j = 0; j < 4; j++)
#pragma unroll
            for (int r = 0; r < 4; r++)
              buf[(i * 16 + quad * 4 + r) * 136 + wn * 64 + j * 16 + l16] =
                  f2bf(acc[i][j][r] * rs[r]);
        }
      }
      sync_lds();
#pragma unroll
      for (int it = 0; it < 4; ++it) {
        int q = tid + it * 256;
        int row = q >> 4, colc = q & 15;
        us8 v = *(us8*)&buf[row * 136 + colc * 8];
        *(us8*)&Cb[(size_t)(m0 + h * 64 + row) * ldc + n0 + colc * 8] = v;
      }
    }
  } else {  // EPI 6: QKV
    const bool vreg = (n0 >= 1024);
    if (!vreg) {
      UST* Cb = (UST*)C + (long)z * zC;
#pragma unroll
      for (int h = 0; h < 2; ++h) {
        if (h) barrier_nowait();
        if (wm == h) {
#pragma unroll
          for (int i = 0; i < 4; i++)
#pragma unroll
            for (int j = 0; j < 4; j++) {
              const float bc = bias[n0 + wn * 64 + j * 16 + l16];
#pragma unroll
              for (int r = 0; r < 4; r++)
                buf[(i * 16 + quad * 4 + r) * 136 + wn * 64 + j * 16 + l16] =
                    f2bf(acc[i][j][r] + bc);
            }
        }
        sync_lds();
#pragma unroll
        for (int it = 0; it < 4; ++it) {
          int q = tid + it * 256;
          int row = q >> 4, colc = q & 15;
          us8 v = *(us8*)&buf[row * 136 + colc * 8];
          *(us8*)&Cb[(size_t)(m0 + h * 64 + row) * ldc + n0 + colc * 8] = v;
        }
      }
    } else {
      // V: transpose to (c, m); vectorized ushort4 LDS writes (r contiguous)
      UST* Vb = (UST*)extra + (long)z * 524288;
#pragma unroll
      for (int h = 0; h < 2; ++h) {
        if (h) barrier_nowait();
        if (wn == h) {
#pragma unroll
          for (int i = 0; i < 4; i++)
#pragma unroll
            for (int j = 0; j < 4; j++) {
              const float bc = bias[n0 + wn * 64 + j * 16 + l16];
              ushort4 sv;
              sv.x = f2bf(acc[i][j][0] + bc);
              sv.y = f2bf(acc[i][j][1] + bc);
              sv.z = f2bf(acc[i][j][2] + bc);
              sv.w = f2bf(acc[i][j][3] + bc);
              *(ushort4*)&buf[(j * 16 + l16) * 136 + wm * 64 + i * 16 + quad * 4] = sv;
            }
        }
        sync_lds();
#pragma unroll
        for (int it = 0; it < 4; ++it) {
          int q = tid + it * 256;
          int c = q >> 4, mc = q & 15;
          us8 v = *(us8*)&buf[c * 136 + mc * 8];
          *(us8*)&Vb[(size_t)(n0 - 1024 + h * 64 + c) * 1024 + m0 + mc * 8] = v;
        }
      }
    }
  }
#undef STAGE
}

extern "C" void kernel_launch(void* const* d_in, const int* in_sizes, int n_in,
                              void* d_out, int out_size, void* d_ws, size_t ws_size,
                              hipStream_t stream) {
  const float* inp   = (const float*)d_in[0];
  const float* gamma = (const float*)d_in[1];
  const float* beta  = (const float*)d_in[2];
  const float* Wq    = (const float*)d_in[3];
  const float* bq    = (const float*)d_in[4];
  const float* Wk    = (const float*)d_in[5];
  const float* bk    = (const float*)d_in[6];
  const float* Wv    = (const float*)d_in[7];
  const float* bv    = (const float*)d_in[8];
  const float* Wo    = (const float*)d_in[9];
  const float* bo    = (const float*)d_in[10];
  float* out = (float*)d_out;
  char* ws = (char*)d_ws;

  UST*   Xnt   = (UST*)(ws);                           // 16 MB interleaved; reused as At
  UST*   QKt   = (UST*)(ws + ((size_t)16 << 20));      // 32 MB (b,n,1024)
  UST*   V     = (UST*)(ws + ((size_t)48 << 20));      // 16 MB (b,c,m)
  UST*   P     = (UST*)(ws + ((size_t)64 << 20));      // 32 MB (b,n,m) = exp(S)
  float* bqkv  = (float*)(ws + ((size_t)96 << 20));    // 6 KB
  UST*   Wqkvb = (UST*)(ws + ((size_t)96 << 20) + 8192);  // 1.5 MB (1536x512)
  UST*   Wob   = Wqkvb + 786432;                       // 512 KB
  float* l     = (float*)(ws + ((size_t)100 << 20));   // 64 KB: 16 batches x 1024 rows
  UST*   At    = Xnt;

  prep<<<784, 256, 0, stream>>>(
      inp, gamma, beta, Xnt,
      (const float4*)Wq, (const float4*)Wk, (const float4*)Wv, (const float4*)Wo,
      (ushort4*)Wqkvb, (ushort4*)Wob,
      (const float4*)bq, (const float4*)bk, (const float4*)bv, (float4*)bqkv,
      (float4*)l);

  // QKV: rows n (per batch), cols 0..1023 -> QKt ; cols 1024..1535 -> V (transposed)
  gemm_bt<6, 12, 1, 0><<<dim3(12, 8, 16), 256, 0, stream>>>(
      Xnt, Wqkvb, QKt, bqkv, (const float*)V, 1.f,
      512, 1024, 8, 8192, 32768, 512, 8, 32, 524288, 0, 1048576);
  // P(b: 1024x1024) = exp(Q_b @ K_b^T / sqrt(512)), row sums -> l (atomic)
  gemm_bt<7, 8, 0, 0><<<dim3(8, 8, 16), 256, 0, stream>>>(
      QKt, QKt + 512, P, nullptr, (const float*)l, 0.04419417382415922f,
      512, 1024, 1024, 8, 32, 1024, 8, 32, 1048576, 1048576, 1048576);
  // At(b: 1024x512) = (P_b @ V_b^T) / l[row]
  gemm_bt<8, 4, 0, 0><<<dim3(4, 8, 16), 256, 0, stream>>>(
      P, V, At, (const float*)l, nullptr, 1.f,
      1024, 512, 1024, 8, 32, 1024, 8, 32, 1048576, 524288, 524288);
  // out(b: 512x1024) = Wo @ At_b^T + bo[row] + inp (residual)
  gemm_bt<4, 8, 0, 0><<<dim3(8, 4, 16), 256, 0, stream>>>(
      Wob, At, out, bo, inp, 1.f,
      512, 1024, 512, 8, 32, 512, 8, 32, 0, 524288, 524288);
}

// Round 4
// 213.359 us; speedup vs baseline: 2.5052x; 2.5052x over previous
//
#include <hip/hip_runtime.h>

typedef unsigned short UST;
typedef __attribute__((ext_vector_type(8))) short bf16x8;
typedef __attribute__((ext_vector_type(8))) unsigned short us8;
typedef __attribute__((ext_vector_type(4))) float f32x4;

__device__ __forceinline__ UST f2bf(float f) {
  union { float f; unsigned int u; } x; x.f = f;
  unsigned int r = x.u + 0x7fffu + ((x.u >> 16) & 1u);
  return (UST)(r >> 16);
}
__device__ __forceinline__ float bf2f(UST h) {
  union { unsigned int u; float f; } x; x.u = ((unsigned int)h) << 16;
  return x.f;
}

// sync_lds drains LDS ops only (NOT vmcnt) then barriers.
__device__ __forceinline__ void sync_lds() {
  asm volatile("s_waitcnt lgkmcnt(0)\n\ts_barrier" ::: "memory");
}
__device__ __forceinline__ void barrier_nowait() {
  asm volatile("s_barrier" ::: "memory");
}

typedef const __attribute__((address_space(1))) void g_void;
typedef __attribute__((address_space(3))) void lds_void;
// async global->LDS, 16B per lane; LDS dest = wave-uniform base + lane*16
__device__ __forceinline__ void gload16(const UST* g, UST* l) {
  __builtin_amdgcn_global_load_lds((g_void*)g, (lds_void*)l, 16, 0, 0);
}

// ---- prep: GroupNorm (0..511, SINGLE PASS: data lives in 64 VGPRs) ---------
// + weight conversion (512..767) + zero l (768..783)
// Xnt layout per batch: element (n,c) at (c>>3)*8192 + n*8 + (c&7)  [bf16]
__global__ __launch_bounds__(256) void prep(
    const float* __restrict__ inp, const float* __restrict__ gamma,
    const float* __restrict__ beta, UST* __restrict__ Xnt,
    const float4* __restrict__ wq, const float4* __restrict__ wk,
    const float4* __restrict__ wv, const float4* __restrict__ wo,
    ushort4* __restrict__ oqkv, ushort4* __restrict__ owo,
    const float4* __restrict__ bq4, const float4* __restrict__ bk4,
    const float4* __restrict__ bv4, float4* __restrict__ bqkv4,
    float4* __restrict__ l4) {
  const int tid = threadIdx.x;
  if (blockIdx.x >= 768) {  // zero the softmax-denominator array (16384 f32)
    int i = (blockIdx.x - 768) * 256 + tid;
    l4[i] = make_float4(0.f, 0.f, 0.f, 0.f);
    return;
  }
  if (blockIdx.x >= 512) {
    const int wb = blockIdx.x - 512;       // 0..255
    int i = wb * 256 + tid;                // 65536 float4 per matrix
    float4 v;
    v = wq[i]; oqkv[i]          = make_ushort4(f2bf(v.x), f2bf(v.y), f2bf(v.z), f2bf(v.w));
    v = wk[i]; oqkv[i + 65536]  = make_ushort4(f2bf(v.x), f2bf(v.y), f2bf(v.z), f2bf(v.w));
    v = wv[i]; oqkv[i + 131072] = make_ushort4(f2bf(v.x), f2bf(v.y), f2bf(v.z), f2bf(v.w));
    v = wo[i]; owo[i]           = make_ushort4(f2bf(v.x), f2bf(v.y), f2bf(v.z), f2bf(v.w));
    if (wb < 2) {
      int t = wb * 256 + tid;
      if (t < 384) bqkv4[t] = (t < 128) ? bq4[t] : (t < 256 ? bk4[t - 128] : bv4[t - 256]);
    }
    return;
  }
  // GroupNorm: one block per (batch b, group g). Group = 16 channels x 1024 px
  // = 64KB fp32 = 64 floats/thread: thread holds channel c_local=i, n=4*tid+m.
  const int g = blockIdx.x & 31, b = blockIdx.x >> 5;
  const float4* p4 = (const float4*)(inp + ((size_t)b * 32 + g) * 16384);
  float x[16][4];
  float s = 0.f, ss = 0.f;
#pragma unroll
  for (int i = 0; i < 16; i++) {
    float4 t = p4[tid + i * 256];
    x[i][0] = t.x; x[i][1] = t.y; x[i][2] = t.z; x[i][3] = t.w;
    s += t.x + t.y + t.z + t.w;
    ss += t.x * t.x + t.y * t.y + t.z * t.z + t.w * t.w;
  }
  for (int o = 32; o >= 1; o >>= 1) { s += __shfl_xor(s, o); ss += __shfl_xor(ss, o); }
  __shared__ float red[8];
  __shared__ float mu_s, rstd_s;
  const int w = tid >> 6;
  if ((tid & 63) == 0) { red[w * 2] = s; red[w * 2 + 1] = ss; }
  __syncthreads();
  if (tid == 0) {
    float S1 = red[0] + red[2] + red[4] + red[6];
    float S2 = red[1] + red[3] + red[5] + red[7];
    float mu = S1 * (1.f / 16384.f);
    float var = S2 * (1.f / 16384.f) - mu * mu;
    mu_s = mu; rstd_s = rsqrtf(var + 1e-6f);
  }
  __syncthreads();
  const float mu = mu_s, rstd = rstd_s;
#pragma unroll
  for (int o2 = 0; o2 < 2; o2++) {
    const int ccg = g * 2 + o2;
    float sc[8], sh[8];
#pragma unroll
    for (int j = 0; j < 8; j++) {
      int ch = ccg * 8 + j;
      sc[j] = gamma[ch] * rstd;
      sh[j] = beta[ch] - mu * sc[j];
    }
#pragma unroll
    for (int m = 0; m < 4; m++) {
      us8 v;
#pragma unroll
      for (int j = 0; j < 8; j++) v[j] = f2bf(x[o2 * 8 + j][m] * sc[j] + sh[j]);
      *(us8*)(Xnt + (size_t)b * 524288 + (size_t)ccg * 8192 + (size_t)(4 * tid + m) * 8) = v;
    }
  }
}

// ---- gemm_bt v5: C[i][j] = sum_k A[i][k]*B[j][k] ---------------------------
// 128x128 tile, 4 waves of 64x64, 16 MFMA/iter. Staging: global_load_lds
// direct to LDS, TWO 16KB buffers = 32KB. __launch_bounds__(256,4): 16
// waves/CU with VGPR cap 128 (r3 lesson: (256,5) forced VGPR=48 -> acc
// spilled to scratch, WRITE_SIZE 49->422MB, 177us/dispatch. 64-float acc
// makes 4 waves/SIMD the hardware max).
// Depth-2 counted prefetch: steady state 8 loads outstanding, s_waitcnt
// vmcnt(4) per iter (drain only at last iter). Two barriers/iter, STAGE(k+2)
// issued right after the read-completion barrier.
// Staging scheme per operand (AR/BR template flags):
//   row-minor (AR=1, for Xnt rs==8): LDS = [kc-plane 2KB][row*16B]; global
//     loads 1KB contiguous per instr; reads swizzle-free, 2-way/phase (floor).
//   kc-minor (0, row-major operands): LDS = [row][slot] pitch 32 UST with
//     XOR content swizzle (slot c holds chunk c^s(row), s=((r>>1)^(r>>3))&3)
//     applied on the GLOBAL source address (LDS dest linear, rule #21) and on
//     the ds_read side -> 2-way/phase (floor).
// EPI 6: QKV - bf16 +bias[col]; n0<1024 -> QKt row-major; n0>=1024 -> V
//        transposed into (c,m) layout (V base via `extra`, z-stride 524288)
// EPI 7: P = exp(acc*scale) bf16 + per-row sum atomicAdd into `extra` (l array)
// EPI 8: bf16, acc * (1/l[row]) with l via `bias`  (softmax denominator)
// EPI 4: f32 +bias[row] +extra (residual)
template <int EPI, int NT, int AR, int BR>
__global__ __launch_bounds__(256, 4) void gemm_bt(
    const UST* __restrict__ A, const UST* __restrict__ B, void* __restrict__ C,
    const float* __restrict__ bias, const float* __restrict__ extra, float scale,
    int K, int ldc,
    int rsA, int csA, int ssA, int rsB, int csB, int ssB,
    long zA, long zB, long zC) {
  // 32KB: two (A 8KB + B 8KB) staging buffers; epilogue aliases buf.
  __shared__ __align__(16) UST buf[16384];

  const int tid = threadIdx.x;
  int m0, n0, z;
  if constexpr (NT > 0) {
    int lin = blockIdx.x + NT * (blockIdx.y + gridDim.y * blockIdx.z);
    int T = gridDim.y * gridDim.z;      // total A-tiles (multiple of 8)
    int per = T >> 3;                   // A-tiles per XCD
    int g = lin & 7, idx = lin >> 3;
    int at = g * per + idx / NT;
    int x = idx % NT;
    m0 = (at % gridDim.y) * 128; z = at / gridDim.y; n0 = x * 128;
  } else {
    m0 = blockIdx.y * 128; n0 = blockIdx.x * 128; z = blockIdx.z;
  }
  const UST* Ab = A + (long)z * zA;
  const UST* Bb = B + (long)z * zB;

  const int w = tid >> 6, lane = tid & 63;
  const int quad = lane >> 4, l16 = lane & 15;
  const int wm = w >> 1, wn = w & 1;  // 2x2 waves, each 64x64

  f32x4 acc[4][4];
#pragma unroll
  for (int i = 0; i < 4; i++)
#pragma unroll
    for (int j = 0; j < 4; j++) acc[i][j] = f32x4{0.f, 0.f, 0.f, 0.f};

  // Staging source pointers: 2 rounds each for A and B (512 16B-chunks each).
  const UST* gA[2];
  const UST* gB[2];
#pragma unroll
  for (int t = 0; t < 2; t++) {
    int q = t * 256 + w * 64 + lane;
    int row, kc;
    if constexpr (AR) { kc = q >> 7; row = q & 127; }
    else {
      row = q >> 2; int kk = q & 3;
      kc = kk ^ (((row >> 1) ^ (row >> 3)) & 3);
    }
    gA[t] = Ab + (size_t)(m0 + row) * rsA + (size_t)kc * csA;
  }
#pragma unroll
  for (int t = 0; t < 2; t++) {
    int q = t * 256 + w * 64 + lane;
    int row, kc;
    if constexpr (BR) { kc = q >> 7; row = q & 127; }
    else {
      row = q >> 2; int kk = q & 3;
      kc = kk ^ (((row >> 1) ^ (row >> 3)) & 3);
    }
    gB[t] = Bb + (size_t)(n0 + row) * rsB + (size_t)kc * csB;
  }
  // LDS fragment read offsets (loop-invariant, UST units)
  int aoff[4], boff[4];
#pragma unroll
  for (int i = 0; i < 4; i++) {
    int R = wm * 64 + i * 16 + l16;
    if constexpr (AR) aoff[i] = quad * 1024 + R * 8;
    else {
      int s = ((R >> 1) ^ (R >> 3)) & 3;
      aoff[i] = R * 32 + (quad ^ s) * 8;
    }
  }
#pragma unroll
  for (int j = 0; j < 4; j++) {
    int R = wn * 64 + j * 16 + l16;
    if constexpr (BR) boff[j] = quad * 1024 + R * 8;
    else {
      int s = ((R >> 1) ^ (R >> 3)) & 3;
      boff[j] = R * 32 + (quad ^ s) * 8;
    }
  }

  const int nk = K >> 5;

#define STAGE(bb)                                   \
  {                                                 \
    UST* sA = buf + (bb) * 8192;                    \
    UST* sB = sA + 4096;                            \
    _Pragma("unroll") for (int t = 0; t < 2; t++) { \
      gload16(gA[t], sA + t * 2048 + w * 512);      \
      gA[t] += ssA;                                 \
    }                                               \
    _Pragma("unroll") for (int t = 0; t < 2; t++) { \
      gload16(gB[t], sB + t * 2048 + w * 512);      \
      gB[t] += ssB;                                 \
    }                                               \
  }

  STAGE(0)
  STAGE(1)

  for (int k = 0; k < nk; ++k) {
    // wait for OWN buf[k&1] loads (oldest 4); barrier makes it global.
    if (k + 1 < nk) asm volatile("s_waitcnt vmcnt(4)" ::: "memory");
    else            asm volatile("s_waitcnt vmcnt(0)" ::: "memory");
    barrier_nowait();
    const UST* cA = buf + (k & 1) * 8192;
    const UST* cB = cA + 4096;
    bf16x8 af[4], bfr[4];
#pragma unroll
    for (int i = 0; i < 4; i++) af[i] = *(const bf16x8*)(cA + aoff[i]);
#pragma unroll
    for (int j = 0; j < 4; j++) bfr[j] = *(const bf16x8*)(cB + boff[j]);
    __builtin_amdgcn_s_setprio(1);
#pragma unroll
    for (int i = 0; i < 4; i++)
#pragma unroll
      for (int j = 0; j < 4; j++)
        acc[i][j] = __builtin_amdgcn_mfma_f32_16x16x32_bf16(af[i], bfr[j], acc[i][j], 0, 0, 0);
    __builtin_amdgcn_s_setprio(0);
    if (k + 2 < nk) {
      sync_lds();     // all waves' reads of buf[k&1] done -> safe to overwrite
      STAGE(k & 1)
    }
  }
  sync_lds();  // pre-epilogue barrier (staging -> C-tile reuse)

  // C/D layout (verified m89/m91): col = lane&15, row = quad*4 + reg
  if constexpr (EPI == 4) {
    // fp32 out + bias[row] + residual; four 32-row x 132-float phases
    float* fbuf = (float*)buf;
    float* Cb = (float*)C + (long)z * zC;
    const float* Eb = extra + (long)z * zC;
#pragma unroll
    for (int p = 0; p < 4; ++p) {
      if (p) barrier_nowait();
      if (wm == (p >> 1)) {
#pragma unroll
        for (int ii = 0; ii < 2; ii++) {
          const int i = (p & 1) * 2 + ii;
#pragma unroll
          for (int j = 0; j < 4; j++)
#pragma unroll
            for (int r = 0; r < 4; r++)
              fbuf[(ii * 16 + quad * 4 + r) * 132 + wn * 64 + j * 16 + l16] = acc[i][j][r];
        }
      }
      sync_lds();
#pragma unroll
      for (int it = 0; it < 4; ++it) {
        int q = tid + it * 256;
        int row = q >> 5, colc = q & 31;
        int gr = m0 + p * 32 + row;
        size_t off = (size_t)gr * ldc + n0 + colc * 4;
        float4 v = *(float4*)&fbuf[row * 132 + colc * 4];
        float4 e = *(const float4*)&Eb[off];
        float bb = bias[gr];
        v.x += bb + e.x; v.y += bb + e.y; v.z += bb + e.z; v.w += bb + e.w;
        *(float4*)&Cb[off] = v;
      }
    }
  } else if constexpr (EPI == 7) {
    // P = exp(acc*scale) bf16 + per-row partial sums atomically into l
    UST* Cb = (UST*)C + (long)z * zC;
    float* lrow = (float*)extra + (long)z * 1024;
#pragma unroll
    for (int h = 0; h < 2; ++h) {
      if (h) barrier_nowait();
      if (wm == h) {
#pragma unroll
        for (int i = 0; i < 4; i++)
#pragma unroll
          for (int j = 0; j < 4; j++)
#pragma unroll
            for (int r = 0; r < 4; r++) {
              float v = __expf(acc[i][j][r] * scale);
              buf[(i * 16 + quad * 4 + r) * 136 + wn * 64 + j * 16 + l16] = f2bf(v);
            }
      }
      sync_lds();
#pragma unroll
      for (int it = 0; it < 4; ++it) {
        int q = tid + it * 256;
        int row = q >> 4, colc = q & 15;  // 64 rows x 16 us8
        us8 v = *(us8*)&buf[row * 136 + colc * 8];
        *(us8*)&Cb[(size_t)(m0 + h * 64 + row) * ldc + n0 + colc * 8] = v;
        float s = 0.f;
#pragma unroll
        for (int j = 0; j < 8; j++) s += bf2f(v[j]);
        s += __shfl_xor(s, 8); s += __shfl_xor(s, 4);
        s += __shfl_xor(s, 2); s += __shfl_xor(s, 1);
        if ((lane & 15) == 0) atomicAdd(&lrow[m0 + h * 64 + row], s);
      }
    }
  } else if constexpr (EPI == 8) {
    // At = acc / l[row]  (softmax denominator), bf16 row-major
    UST* Cb = (UST*)C + (long)z * zC;
    const float* lrow = bias + (long)z * 1024;
#pragma unroll
    for (int h = 0; h < 2; ++h) {
      if (h) barrier_nowait();
      if (wm == h) {
#pragma unroll
        for (int i = 0; i < 4; i++) {
          float rs[4];
#pragma unroll
          for (int r = 0; r < 4; r++)
            rs[r] = 1.0f / lrow[m0 + h * 64 + i * 16 + quad * 4 + r];
#pragma unroll
          for (int j = 0; j < 4; j++)
#pragma unroll
            for (int r = 0; r < 4; r++)
              buf[(i * 16 + quad * 4 + r) * 136 + wn * 64 + j * 16 + l16] =
                  f2bf(acc[i][j][r] * rs[r]);
        }
      }
      sync_lds();
#pragma unroll
      for (int it = 0; it < 4; ++it) {
        int q = tid + it * 256;
        int row = q >> 4, colc = q & 15;
        us8 v = *(us8*)&buf[row * 136 + colc * 8];
        *(us8*)&Cb[(size_t)(m0 + h * 64 + row) * ldc + n0 + colc * 8] = v;
      }
    }
  } else {  // EPI 6: QKV
    const bool vreg = (n0 >= 1024);
    if (!vreg) {
      UST* Cb = (UST*)C + (long)z * zC;
#pragma unroll
      for (int h = 0; h < 2; ++h) {
        if (h) barrier_nowait();
        if (wm == h) {
#pragma unroll
          for (int i = 0; i < 4; i++)
#pragma unroll
            for (int j = 0; j < 4; j++) {
              const float bc = bias[n0 + wn * 64 + j * 16 + l16];
#pragma unroll
              for (int r = 0; r < 4; r++)
                buf[(i * 16 + quad * 4 + r) * 136 + wn * 64 + j * 16 + l16] =
                    f2bf(acc[i][j][r] + bc);
            }
        }
        sync_lds();
#pragma unroll
        for (int it = 0; it < 4; ++it) {
          int q = tid + it * 256;
          int row = q >> 4, colc = q & 15;
          us8 v = *(us8*)&buf[row * 136 + colc * 8];
          *(us8*)&Cb[(size_t)(m0 + h * 64 + row) * ldc + n0 + colc * 8] = v;
        }
      }
    } else {
      // V: transpose to (c, m); vectorized ushort4 LDS writes (r contiguous)
      UST* Vb = (UST*)extra + (long)z * 524288;
#pragma unroll
      for (int h = 0; h < 2; ++h) {
        if (h) barrier_nowait();
        if (wn == h) {
#pragma unroll
          for (int i = 0; i < 4; i++)
#pragma unroll
            for (int j = 0; j < 4; j++) {
              const float bc = bias[n0 + wn * 64 + j * 16 + l16];
              ushort4 sv;
              sv.x = f2bf(acc[i][j][0] + bc);
              sv.y = f2bf(acc[i][j][1] + bc);
              sv.z = f2bf(acc[i][j][2] + bc);
              sv.w = f2bf(acc[i][j][3] + bc);
              *(ushort4*)&buf[(j * 16 + l16) * 136 + wm * 64 + i * 16 + quad * 4] = sv;
            }
        }
        sync_lds();
#pragma unroll
        for (int it = 0; it < 4; ++it) {
          int q = tid + it * 256;
          int c = q >> 4, mc = q & 15;
          us8 v = *(us8*)&buf[c * 136 + mc * 8];
          *(us8*)&Vb[(size_t)(n0 - 1024 + h * 64 + c) * 1024 + m0 + mc * 8] = v;
        }
      }
    }
  }
#undef STAGE
}

extern "C" void kernel_launch(void* const* d_in, const int* in_sizes, int n_in,
                              void* d_out, int out_size, void* d_ws, size_t ws_size,
                              hipStream_t stream) {
  const float* inp   = (const float*)d_in[0];
  const float* gamma = (const float*)d_in[1];
  const float* beta  = (const float*)d_in[2];
  const float* Wq    = (const float*)d_in[3];
  const float* bq    = (const float*)d_in[4];
  const float* Wk    = (const float*)d_in[5];
  const float* bk    = (const float*)d_in[6];
  const float* Wv    = (const float*)d_in[7];
  const float* bv    = (const float*)d_in[8];
  const float* Wo    = (const float*)d_in[9];
  const float* bo    = (const float*)d_in[10];
  float* out = (float*)d_out;
  char* ws = (char*)d_ws;

  UST*   Xnt   = (UST*)(ws);                           // 16 MB interleaved; reused as At
  UST*   QKt   = (UST*)(ws + ((size_t)16 << 20));      // 32 MB (b,n,1024)
  UST*   V     = (UST*)(ws + ((size_t)48 << 20));      // 16 MB (b,c,m)
  UST*   P     = (UST*)(ws + ((size_t)64 << 20));      // 32 MB (b,n,m) = exp(S)
  float* bqkv  = (float*)(ws + ((size_t)96 << 20));    // 6 KB
  UST*   Wqkvb = (UST*)(ws + ((size_t)96 << 20) + 8192);  // 1.5 MB (1536x512)
  UST*   Wob   = Wqkvb + 786432;                       // 512 KB
  float* l     = (float*)(ws + ((size_t)100 << 20));   // 64 KB: 16 batches x 1024 rows
  UST*   At    = Xnt;

  prep<<<784, 256, 0, stream>>>(
      inp, gamma, beta, Xnt,
      (const float4*)Wq, (const float4*)Wk, (const float4*)Wv, (const float4*)Wo,
      (ushort4*)Wqkvb, (ushort4*)Wob,
      (const float4*)bq, (const float4*)bk, (const float4*)bv, (float4*)bqkv,
      (float4*)l);

  // QKV: rows n (per batch), cols 0..1023 -> QKt ; cols 1024..1535 -> V (transposed)
  gemm_bt<6, 12, 1, 0><<<dim3(12, 8, 16), 256, 0, stream>>>(
      Xnt, Wqkvb, QKt, bqkv, (const float*)V, 1.f,
      512, 1024, 8, 8192, 32768, 512, 8, 32, 524288, 0, 1048576);
  // P(b: 1024x1024) = exp(Q_b @ K_b^T / sqrt(512)), row sums -> l (atomic)
  gemm_bt<7, 8, 0, 0><<<dim3(8, 8, 16), 256, 0, stream>>>(
      QKt, QKt + 512, P, nullptr, (const float*)l, 0.04419417382415922f,
      512, 1024, 1024, 8, 32, 1024, 8, 32, 1048576, 1048576, 1048576);
  // At(b: 1024x512) = (P_b @ V_b^T) / l[row]
  gemm_bt<8, 4, 0, 0><<<dim3(4, 8, 16), 256, 0, stream>>>(
      P, V, At, (const float*)l, nullptr, 1.f,
      1024, 512, 1024, 8, 32, 1024, 8, 32, 1048576, 524288, 524288);
  // out(b: 512x1024) = Wo @ At_b^T + bo[row] + inp (residual)
  gemm_bt<4, 8, 0, 0><<<dim3(8, 4, 16), 256, 0, stream>>>(
      Wob, At, out, bo, inp, 1.f,
      512, 1024, 512, 8, 32, 512, 8, 32, 0, 524288, 524288);
}